// Round 5
// baseline (409.559 us; speedup 1.0000x reference)
//
#include <hip/hip_runtime.h>
#include <stdint.h>

#define PARTITIONABLE 1

namespace {

// ---------------- Threefry-2x32 (constexpr, host+device) ----------------
struct TFPair { uint32_t a, b; };

__host__ __device__ constexpr uint32_t rotl32(uint32_t x, int d) {
  return (x << d) | (x >> (32 - d));
}

__host__ __device__ constexpr TFPair tf2x32(uint32_t k0, uint32_t k1,
                                            uint32_t x0, uint32_t x1) {
  uint32_t k2 = k0 ^ k1 ^ 0x1BD11BDAu;
  x0 += k0; x1 += k1;
  x0 += x1; x1 = rotl32(x1, 13); x1 ^= x0;
  x0 += x1; x1 = rotl32(x1, 15); x1 ^= x0;
  x0 += x1; x1 = rotl32(x1, 26); x1 ^= x0;
  x0 += x1; x1 = rotl32(x1, 6);  x1 ^= x0;
  x0 += k1; x1 += k2 + 1u;
  x0 += x1; x1 = rotl32(x1, 17); x1 ^= x0;
  x0 += x1; x1 = rotl32(x1, 29); x1 ^= x0;
  x0 += x1; x1 = rotl32(x1, 16); x1 ^= x0;
  x0 += x1; x1 = rotl32(x1, 24); x1 ^= x0;
  x0 += k2; x1 += k0 + 2u;
  x0 += x1; x1 = rotl32(x1, 13); x1 ^= x0;
  x0 += x1; x1 = rotl32(x1, 15); x1 ^= x0;
  x0 += x1; x1 = rotl32(x1, 26); x1 ^= x0;
  x0 += x1; x1 = rotl32(x1, 6);  x1 ^= x0;
  x0 += k0; x1 += k1 + 3u;
  x0 += x1; x1 = rotl32(x1, 17); x1 ^= x0;
  x0 += x1; x1 = rotl32(x1, 29); x1 ^= x0;
  x0 += x1; x1 = rotl32(x1, 16); x1 ^= x0;
  x0 += x1; x1 = rotl32(x1, 24); x1 ^= x0;
  x0 += k1; x1 += k2 + 4u;
  x0 += x1; x1 = rotl32(x1, 13); x1 ^= x0;
  x0 += x1; x1 = rotl32(x1, 15); x1 ^= x0;
  x0 += x1; x1 = rotl32(x1, 26); x1 ^= x0;
  x0 += x1; x1 = rotl32(x1, 6);  x1 ^= x0;
  x0 += k2; x1 += k0 + 5u;
  return TFPair{x0, x1};
}

#if PARTITIONABLE
constexpr TFPair KG  = tf2x32(0u, 42u, 0u, 0u);
constexpr TFPair KS  = tf2x32(0u, 42u, 0u, 1u);
constexpr TFPair KA  = tf2x32(0u, 42u, 0u, 2u);
constexpr TFPair KE  = tf2x32(0u, 42u, 0u, 3u);
constexpr TFPair KD  = tf2x32(0u, 42u, 0u, 4u);
constexpr TFPair DK0 = tf2x32(KD.a, KD.b, 0u, 0u);
constexpr TFPair DK1 = tf2x32(KD.a, KD.b, 0u, 1u);
constexpr TFPair DK2 = tf2x32(KD.a, KD.b, 0u, 2u);
#else
constexpr TFPair SP0 = tf2x32(0u, 42u, 0u, 5u);
constexpr TFPair SP1 = tf2x32(0u, 42u, 1u, 6u);
constexpr TFPair SP2 = tf2x32(0u, 42u, 2u, 7u);
constexpr TFPair SP3 = tf2x32(0u, 42u, 3u, 8u);
constexpr TFPair SP4 = tf2x32(0u, 42u, 4u, 9u);
constexpr TFPair KG  = TFPair{SP0.a, SP1.a};
constexpr TFPair KS  = TFPair{SP2.a, SP3.a};
constexpr TFPair KA  = TFPair{SP4.a, SP0.b};
constexpr TFPair KE  = TFPair{SP1.b, SP2.b};
constexpr TFPair KD  = TFPair{SP3.b, SP4.b};
constexpr TFPair DP0 = tf2x32(KD.a, KD.b, 0u, 3u);
constexpr TFPair DP1 = tf2x32(KD.a, KD.b, 1u, 4u);
constexpr TFPair DP2 = tf2x32(KD.a, KD.b, 2u, 5u);
constexpr TFPair DK0 = TFPair{DP0.a, DP1.a};
constexpr TFPair DK1 = TFPair{DP2.a, DP0.b};
constexpr TFPair DK2 = TFPair{DP1.b, DP2.b};
#endif

__device__ __forceinline__ uint32_t rbits(uint32_t k0, uint32_t k1,
                                          uint32_t idx, uint32_t half) {
#if PARTITIONABLE
  TFPair t = tf2x32(k0, k1, 0u, idx);
  return t.a ^ t.b;
#else
  if (idx < half) return tf2x32(k0, k1, idx, idx + half).a;
  return tf2x32(k0, k1, idx - half, idx).b;
#endif
}

__device__ __forceinline__ float bits_to_u01(uint32_t bits) {
  return __uint_as_float((bits >> 9) | 0x3F800000u) - 1.0f;
}

__device__ __forceinline__ float gumbel_u(uint32_t k0, uint32_t k1,
                                          uint32_t idx, uint32_t half) {
  const float mn = 1e-6f;
  const float mx = 1.0f - 1e-6f;
  float f = bits_to_u01(rbits(k0, k1, idx, half));
  return fmaxf(mn, f * (mx - mn) + mn);
}

__device__ __forceinline__ float erfinv_f32(float x) {
  float w = -log1pf(-x * x);
  float p;
  if (w < 5.0f) {
    w -= 2.5f;
    p = 2.81022636e-08f;
    p = fmaf(p, w, 3.43273939e-07f);
    p = fmaf(p, w, -3.5233877e-06f);
    p = fmaf(p, w, -4.39150654e-06f);
    p = fmaf(p, w, 0.00021858087f);
    p = fmaf(p, w, -0.00125372503f);
    p = fmaf(p, w, -0.00417768164f);
    p = fmaf(p, w, 0.246640727f);
    p = fmaf(p, w, 1.50140941f);
  } else {
    w = sqrtf(w) - 3.0f;
    p = -0.000200214257f;
    p = fmaf(p, w, 0.000100950558f);
    p = fmaf(p, w, 0.00134934322f);
    p = fmaf(p, w, -0.00367342844f);
    p = fmaf(p, w, 0.00573950773f);
    p = fmaf(p, w, -0.0076224613f);
    p = fmaf(p, w, 0.00943887047f);
    p = fmaf(p, w, 1.00167406f);
    p = fmaf(p, w, 2.83297682f);
  }
  return p * x;
}

__device__ __forceinline__ float normal_from(uint32_t k0, uint32_t k1,
                                             uint32_t idx, uint32_t half) {
  const float lo = -0x1.fffffep-1f;
  float f = bits_to_u01(rbits(k0, k1, idx, half));
  float u = fmaxf(lo, f * 2.0f + lo);
  return 1.41421356237f * erfinv_f32(u);
}

__device__ __forceinline__ float gelu_f(float x) {
  return 0.5f * x * (1.0f + erff(x / 1.4142135623730951f));
}
__device__ __forceinline__ float sigmoid_f(float x) {
  return 1.0f / (1.0f + expf(-x));
}

__device__ __forceinline__ float wave_sum(float v) {
  #pragma unroll
  for (int m = 32; m > 0; m >>= 1) v += __shfl_xor(v, m);
  return v;
}
__device__ __forceinline__ float wave_max(float v) {
  #pragma unroll
  for (int m = 32; m > 0; m >>= 1) v = fmaxf(v, __shfl_xor(v, m));
  return v;
}
template <int NW>
__device__ __forceinline__ float blk_sum(float v, float* slots) {
  v = wave_sum(v);
  int wid = threadIdx.x >> 6;
  if ((threadIdx.x & 63) == 0) slots[wid] = v;
  __syncthreads();
  float r = slots[0];
  #pragma unroll
  for (int i = 1; i < NW; ++i) r += slots[i];
  return r;
}
template <int NW>
__device__ __forceinline__ float blk_max(float v, float* slots) {
  v = wave_max(v);
  int wid = threadIdx.x >> 6;
  if ((threadIdx.x & 63) == 0) slots[wid] = v;
  __syncthreads();
  float r = slots[0];
  #pragma unroll
  for (int i = 1; i < NW; ++i) r = fmaxf(r, slots[i]);
  return r;
}

// ---------------- params ----------------
struct Params {
  const float *x, *gW1, *gb1, *glnw, *glnb, *gW2, *gb2, *sW1, *sb1, *sW2, *sb2,
      *aW1, *ab1, *aW2, *ab2, *g2f, *semb, *aemb, *decay_f, *decay_b, *tW, *tb,
      *psi, *log_sigma, *step_logits, *noise_scale, *Wk, *mean_w, *mean_b,
      *lv_w, *lv_b, *dW1, *db1, *dlnw, *dlnb, *mW, *mb, *lvW, *lvb;
  float* out;
  float *ps, *ds, *hgG, *hgS, *hgA, *fg, *ctx, *v, *sv, *u, *Pf, *Qf, *Pb, *Qb,
      *Lf, *Lb, *YH, *R1, *R2, *gm, *glv, *A, *A2;
};

// ---------------- device phases ----------------

__device__ __forceinline__ void phase_hidden(const Params& P, float* smem,
                                             int bid, int tid) {
  float* inv = smem;
  float* s1 = smem + 256;
  float* s2 = smem + 260;
  int head = bid >> 4, b = bid & 15;
  float iv;
  if (head < 2) {
    float s = 0.f;
    for (int tc = 0; tc < 16; ++tc) s += P.ps[(size_t)(b * 16 + tc) * 256 + tid];
    iv = s / 512.0f;
  } else {
    iv = P.ds[b * 256 + tid];
  }
  inv[tid] = iv;
  __syncthreads();
  const float* W1 = (head == 0) ? P.gW1 : (head == 1) ? P.sW1 : P.aW1;
  const float* b1 = (head == 0) ? P.gb1 : (head == 1) ? P.sb1 : P.ab1;
  float h = b1[tid];
  for (int d = 0; d < 256; ++d) h = fmaf(inv[d], W1[d * 256 + tid], h);
  if (head == 0) {
    float mean = blk_sum<4>(h, s1) / 256.0f;
    float dv = h - mean;
    float var = blk_sum<4>(dv * dv, s2) / 256.0f;
    h = dv / sqrtf(var + 1e-5f) * P.glnw[tid] + P.glnb[tid];
  }
  float* outp = (head == 0) ? P.hgG : (head == 1) ? P.hgS : P.hgA;
  outp[b * 256 + tid] = gelu_f(h);
}

__device__ __forceinline__ void phase_vcompute(const Params& P, int bid2,
                                               int tid) {
  int j = bid2 >> 2, tg = bid2 & 3;
  const float* wp = (j & 1) ? P.lv_w : P.mean_w;
  const float* Wkk = P.Wk + (size_t)(j >> 1) * 65536;
  int wid = tid >> 6, lane = tid & 63;
  float w0 = wp[lane], w1 = wp[64 + lane];
  float svloc = 0.f;
  for (int i = 0; i < 32; ++i) {
    int t = tg * 128 + wid * 32 + i;
    const float* row = Wkk + (size_t)t * 128;
    float s = row[lane] * w0 + row[64 + lane] * w1;
    s = wave_sum(s);
    if (lane == 0) { P.v[j * 512 + t] = s; svloc += s; }
  }
  if (lane == 0) atomicAdd(&P.sv[j], svloc);
}

__device__ __forceinline__ void phase_ainit(const Params& P, float* smem,
                                            int row0, int nrows, int tid) {
  float* pn = smem;
  float* s1 = smem + 12;
  float* s2 = smem + 16;
  for (int r = 0; r < nrows; ++r) {
    int blk = row0 + r;
    int mh = blk >> 8, h = mh & 3, n = blk & 255, p = tid;
    if (p < 10) pn[p] = P.psi[(size_t)(h * 256 + n) * 10 + p];
    __syncthreads();
    const float* pp = P.psi + (size_t)(h * 256 + p) * 10;
    float s = 0.f;
    #pragma unroll
    for (int e = 0; e < 10; ++e) s = fmaf(pn[e], pp[e], s);
    float logit = s / sqrtf(10.0f);
    uint32_t idx = (uint32_t)blk * 256u + (uint32_t)p;
    float eps = normal_from(KE.a, KE.b, idx, 524288u);
    float val = logit + expf(P.log_sigma[h]) * eps;
    float mx = blk_max<4>(val, s1);
    float e = expf(val - mx);
    float sum = blk_sum<4>(e, s2);
    P.A[(size_t)blk * 256 + p] = e / sum;
  }
}

__device__ __forceinline__ void phase_gates(const Params& P, float* smem,
                                            int bid, int tid) {
  float* hgGs = smem;
  float* hgSs = smem + 256;
  float* hgAs = smem + 512;
  float* lvS = smem + 768;    // 384
  float* lvA = smem + 1152;   // 256
  float* gsl = smem + 1408;   // 16
  float* gvals = smem + 1424; // 4
  float* gpv = smem + 1428;   // 4
  int b = bid >> 2, f0 = (bid & 3) * 64;
  hgGs[tid] = P.hgG[b * 256 + tid];
  hgSs[tid] = P.hgS[b * 256 + tid];
  hgAs[tid] = P.hgA[b * 256 + tid];
  __syncthreads();
  float lg[4];
  #pragma unroll
  for (int s = 0; s < 4; ++s)
    lg[s] = blk_sum<4>(hgGs[tid] * P.gW2[tid * 4 + s], gsl + 4 * s);
  if (tid < 4) {
    float u = gumbel_u(KG.a, KG.b, (uint32_t)(b * 4 + tid), 32u);
    float g = -logf(-logf(u));
    gvals[tid] = (lg[tid] + P.gb2[tid] + g) / 0.5f;
  }
  __syncthreads();
  if (tid < 4) {
    float mx = fmaxf(fmaxf(gvals[0], gvals[1]), fmaxf(gvals[2], gvals[3]));
    float sum = expf(gvals[0] - mx) + expf(gvals[1] - mx) +
                expf(gvals[2] - mx) + expf(gvals[3] - mx);
    gpv[tid] = expf(gvals[tid] - mx) / sum;
  }
  {
    int o = tid;
    int fl = o / 6, s = o - fl * 6;
    int f = f0 + fl;
    const float* wp = P.sW2 + f * 6 + s;
    float acc = P.sb2[f * 6 + s];
    for (int d = 0; d < 256; ++d) acc = fmaf(hgSs[d], wp[(size_t)d * 1536], acc);
    float u = gumbel_u(KS.a, KS.b, (uint32_t)(b * 256 + f) * 6u + s, 12288u);
    lvS[o] = (acc + (-logf(-logf(u)))) / 0.5f;
  }
  if (tid < 128) {
    int o = tid + 256;
    int fl = o / 6, s = o - fl * 6;
    int f = f0 + fl;
    const float* wp = P.sW2 + f * 6 + s;
    float acc = P.sb2[f * 6 + s];
    for (int d = 0; d < 256; ++d) acc = fmaf(hgSs[d], wp[(size_t)d * 1536], acc);
    float u = gumbel_u(KS.a, KS.b, (uint32_t)(b * 256 + f) * 6u + s, 12288u);
    lvS[o] = (acc + (-logf(-logf(u)))) / 0.5f;
  }
  {
    int fl = tid >> 2, s = tid & 3;
    int f = f0 + fl;
    const float* wp = P.aW2 + f * 4 + s;
    float acc = P.ab2[f * 4 + s];
    for (int d = 0; d < 256; ++d) acc = fmaf(hgAs[d], wp[(size_t)d * 1024], acc);
    float u = gumbel_u(KA.a, KA.b, (uint32_t)(b * 256 + f) * 4u + s, 8192u);
    lvA[tid] = (acc + (-logf(-logf(u)))) / 0.5f;
  }
  __syncthreads();
  if (tid < 64) {
    int f = f0 + tid;
    float v0 = lvS[tid * 6 + 0], v1 = lvS[tid * 6 + 1], v2 = lvS[tid * 6 + 2];
    float v3 = lvS[tid * 6 + 3], v4 = lvS[tid * 6 + 4], v5 = lvS[tid * 6 + 5];
    float mx = fmaxf(fmaxf(fmaxf(v0, v1), fmaxf(v2, v3)), fmaxf(v4, v5));
    float e0 = expf(v0 - mx), e1 = expf(v1 - mx), e2 = expf(v2 - mx);
    float e3 = expf(v3 - mx), e4 = expf(v4 - mx), e5 = expf(v5 - mx);
    float ssum = e0 + e1 + e2 + e3 + e4 + e5;
    float sg = (e0 / ssum) * P.semb[0 * 256 + f] + (e1 / ssum) * P.semb[1 * 256 + f] +
               (e2 / ssum) * P.semb[2 * 256 + f] + (e3 / ssum) * P.semb[3 * 256 + f] +
               (e4 / ssum) * P.semb[4 * 256 + f] + (e5 / ssum) * P.semb[5 * 256 + f];
    float a0 = lvA[tid * 4 + 0], a1 = lvA[tid * 4 + 1];
    float a2 = lvA[tid * 4 + 2], a3 = lvA[tid * 4 + 3];
    float amx = fmaxf(fmaxf(a0, a1), fmaxf(a2, a3));
    float x0 = expf(a0 - amx), x1 = expf(a1 - amx);
    float x2 = expf(a2 - amx), x3 = expf(a3 - amx);
    float asum = x0 + x1 + x2 + x3;
    float ag = (x0 / asum) * P.aemb[0 * 256 + f] + (x1 / asum) * P.aemb[1 * 256 + f] +
               (x2 / asum) * P.aemb[2 * 256 + f] + (x3 / asum) * P.aemb[3 * 256 + f];
    float gg = 0.f;
    #pragma unroll
    for (int s = 0; s < 4; ++s) gg = fmaf(gpv[s], P.g2f[s * 256 + f], gg);
    P.fg[b * 256 + f] = sigmoid_f(gg + sg + ag);
  }
}

__device__ __forceinline__ void phase_ctx(const Params& P, float* smem,
                                          int tid) {
  float* s1 = smem;
  float* s2 = smem + 4;
  float c = 0.f;
  for (int b = 0; b < 16; ++b) c += P.fg[b * 256 + tid];
  c /= 16.0f;
  float ss = blk_sum<4>(c * c, s1);
  float cv = c / (sqrtf(ss) + 1e-6f);
  P.ctx[tid] = cv;
  float S = blk_sum<4>(cv, s2);
  if (tid == 0) P.ctx[256] = S;
}

__device__ __forceinline__ void phase_scan1(const Params& P, float* smem,
                                            int ch, int tid) {
  float* vv = smem;  // [8][32]
  int b = ch >> 4, c = ch & 15;
  int d = tid;
  vv[(d >> 5) * 32 + (d & 31)] = P.v[(d >> 5) * 512 + c * 32 + (d & 31)];
  __syncthreads();
  float g = P.fg[b * 256 + d];
  float af = sigmoid_f(P.decay_f[d]);
  float ab = sigmoid_f(P.decay_b[d]);
  float r_gx[32];
  const float* xp = P.x + ((size_t)b * 512 + c * 32) * 256 + d;
  #pragma unroll
  for (int i = 0; i < 32; ++i) r_gx[i] = xp[(size_t)i * 256] * g;
  float h = 0.f, pw = 1.f;
  float Pr[8], Q[8];
  #pragma unroll
  for (int j = 0; j < 8; ++j) { Pr[j] = 0.f; Q[j] = 0.f; }
  #pragma unroll
  for (int i = 0; i < 32; ++i) {
    h = fmaf(af, h, (1.0f - af) * r_gx[i]);
    pw *= af;
    #pragma unroll
    for (int j = 0; j < 8; ++j) {
      float vj = vv[j * 32 + i];
      Pr[j] = fmaf(h, vj, Pr[j]);
      Q[j] = fmaf(pw, vj, Q[j]);
    }
  }
  size_t base = ((size_t)(b * 16 + c) * 8) * 256 + d;
  #pragma unroll
  for (int j = 0; j < 8; ++j) {
    P.Pf[base + j * 256] = Pr[j];
    P.Qf[base + j * 256] = Q[j];
  }
  P.Lf[(b * 16 + c) * 256 + d] = h;
  h = 0.f; pw = 1.f;
  #pragma unroll
  for (int j = 0; j < 8; ++j) { Pr[j] = 0.f; Q[j] = 0.f; }
  #pragma unroll
  for (int i = 31; i >= 0; --i) {
    h = fmaf(ab, h, (1.0f - ab) * r_gx[i]);
    pw *= ab;
    #pragma unroll
    for (int j = 0; j < 8; ++j) {
      float vj = vv[j * 32 + i];
      Pr[j] = fmaf(h, vj, Pr[j]);
      Q[j] = fmaf(pw, vj, Q[j]);
    }
  }
  #pragma unroll
  for (int j = 0; j < 8; ++j) {
    P.Pb[base + j * 256] = Pr[j];
    P.Qb[base + j * 256] = Q[j];
  }
  P.Lb[(b * 16 + c) * 256 + d] = h;
}

__device__ __forceinline__ void phase_scan2(const Params& P, int blk, int tid) {
  int b = blk >> 3, j = blk & 7;
  int d = tid;
  float af = sigmoid_f(P.decay_f[d]);
  float ab = sigmoid_f(P.decay_b[d]);
  float af32 = af, ab32 = ab;
  #pragma unroll
  for (int q = 0; q < 5; ++q) { af32 *= af32; ab32 *= ab32; }
  float acc = 0.f, H = 0.f;
  for (int c = 0; c < 16; ++c) {
    size_t base = ((size_t)(b * 16 + c) * 8 + j) * 256 + d;
    acc += P.Pf[base] + H * P.Qf[base];
    H = P.Lf[(b * 16 + c) * 256 + d] + af32 * H;
  }
  H = 0.f;
  for (int c = 15; c >= 0; --c) {
    size_t base = ((size_t)(b * 16 + c) * 8 + j) * 256 + d;
    acc += P.Pb[base] + H * P.Qb[base];
    H = P.Lb[(b * 16 + c) * 256 + d] + ab32 * H;
  }
  P.u[(b * 8 + j) * 256 + d] = acc;
}

__device__ __forceinline__ void phase_ygemm(const Params& P, float* smem,
                                            int blk32, int tid) {
  float* As = smem;            // 32*33
  float* Bs = smem + 1056;     // 32*33
  float* svs = smem + 2112;    // 8
  int n0 = (blk32 & 7) * 32, m0 = (blk32 >> 3) * 32;
  int tx = tid & 31, ty = tid >> 5;
  if (tid < 8) svs[tid] = P.sv[tid];
  float acc[4] = {0.f, 0.f, 0.f, 0.f};
  for (int k0 = 0; k0 < 256; k0 += 32) {
    #pragma unroll
    for (int l = 0; l < 4; ++l) {
      int e = tid + l * 256, r = e >> 5, cc = e & 31;
      As[r * 33 + cc] = P.u[(size_t)(m0 + r) * 256 + k0 + cc];
      Bs[r * 33 + cc] = P.tW[(size_t)(k0 + r) * 256 + n0 + cc];
    }
    __syncthreads();
    #pragma unroll
    for (int kk = 0; kk < 32; ++kk) {
      float bv = Bs[kk * 33 + tx];
      #pragma unroll
      for (int i = 0; i < 4; ++i)
        acc[i] = fmaf(As[(ty + 8 * i) * 33 + kk], bv, acc[i]);
    }
    __syncthreads();
  }
  int n = n0 + tx;
  float tbn = P.tb[n];
  float mb0 = P.mean_b[0], lb0 = P.lv_b[0];
  #pragma unroll
  for (int i = 0; i < 4; ++i) {
    int row = m0 + ty + 8 * i;
    int b = row >> 3, j = row & 7;
    float val = acc[i] + tbn * svs[j];
    if (j == 0) P.gm[b * 256 + n] = val + mb0;
    else if (j == 1) P.glv[b * 256 + n] = val + lb0;
    else {
      int k = (j >> 1) - 1, proj = j & 1;
      P.YH[k * 8192 + n * 32 + b * 2 + proj] = val;
    }
  }
}

__device__ __forceinline__ void phase_mix(const Params& P, float* smem,
                                          int sidx, const float* Ain,
                                          float* Aout, uint32_t dk0,
                                          uint32_t dk1, int row0, int nrows,
                                          int tid) {
  float* s1 = smem;
  float* s2 = smem + 4;
  float alpha = sigmoid_f(P.step_logits[sidx]);
  float ns = P.noise_scale[sidx];
  float S = P.ctx[256];
  float cp = P.ctx[tid];
  for (int i = 0; i < nrows; ++i) {
    int blk = row0 + i;
    int mh = blk >> 8, n = blk & 255, p = tid;
    float cn = P.ctx[n];
    float o_np = (cn * cp) / fmaxf(cn * S, 1e-6f);
    float o_pn = (cp * cn) / fmaxf(cp * S, 1e-6f);
    uint32_t i_np = (uint32_t)blk * 256u + (uint32_t)p;
    uint32_t i_pn = (uint32_t)mh * 65536u + (uint32_t)p * 256u + (uint32_t)n;
    float a_np = Ain[(size_t)mh * 65536 + n * 256 + p];
    float a_pn = Ain[(size_t)mh * 65536 + p * 256 + n];
    float m_np = alpha * a_np + (1.0f - alpha) * o_np +
                 ns * normal_from(dk0, dk1, i_np, 524288u);
    float m_pn = alpha * a_pn + (1.0f - alpha) * o_pn +
                 ns * normal_from(dk0, dk1, i_pn, 524288u);
    float val = 0.5f * (m_np + m_pn);
    float mx = blk_max<4>(val, s1);
    float e = expf(val - mx);
    float sum = blk_sum<4>(e, s2);
    Aout[(size_t)blk * 256 + p] = e / sum;
  }
}

__device__ __forceinline__ void phase_horner(const Params& P, float* smem,
                                             const float* A, const float* Rin,
                                             int sRin, const float* Yadd,
                                             float* Rout, int bid, int tid) {
  float* As = smem;
  float* Bs = smem + 1056;
  int nt = bid & 7, mh = bid >> 3;
  int n0 = nt * 32;
  int tx = tid & 31, ty = tid >> 5;
  float acc[4] = {0.f, 0.f, 0.f, 0.f};
  const float* Ab = A + (size_t)mh * 65536;
  const float* Rb = Rin + (size_t)mh * sRin;
  for (int k0 = 0; k0 < 256; k0 += 32) {
    #pragma unroll
    for (int l = 0; l < 4; ++l) {
      int e = tid + l * 256, r = e >> 5, cc = e & 31;
      As[r * 33 + cc] = Ab[(size_t)(n0 + r) * 256 + k0 + cc];
      Bs[r * 33 + cc] = Rb[(size_t)(k0 + r) * 32 + cc];
    }
    __syncthreads();
    #pragma unroll
    for (int kk = 0; kk < 32; ++kk) {
      float bv = Bs[kk * 33 + tx];
      #pragma unroll
      for (int i = 0; i < 4; ++i)
        acc[i] = fmaf(As[(ty + 8 * i) * 33 + kk], bv, acc[i]);
    }
    __syncthreads();
  }
  #pragma unroll
  for (int i = 0; i < 4; ++i) {
    int n = n0 + ty + 8 * i;
    float vv = acc[i];
    if (Yadd) vv += Yadd[n * 32 + tx];
    Rout[(size_t)mh * 8192 + (size_t)n * 32 + tx] = vv;
  }
}

__device__ __forceinline__ void phase_findec(const Params& P, float* smem,
                                             int bid, int tid) {
  float* gmv = smem;       // 256
  float* sl = smem + 256;  // 20
  int b = bid;
  float sm_ = 0.f, sl_ = 0.f;
  for (int mh = 0; mh < 16; ++mh) {
    sm_ += P.R1[(size_t)mh * 8192 + tid * 32 + b * 2];
    sl_ += P.R1[(size_t)mh * 8192 + tid * 32 + b * 2 + 1];
  }
  float gmn = P.gm[b * 256 + tid] + sm_ * (1.0f / 16.0f);
  float gln = P.glv[b * 256 + tid] + sl_ * (1.0f / 16.0f);
  gmv[tid] = gmn;
  float se = expf(gln);
  __syncthreads();
  float sumexp = blk_sum<4>(se, sl);
  float h = 0.f;
  if (tid < 128) {
    h = P.db1[tid];
    for (int n = 0; n < 256; ++n) h = fmaf(gmv[n], P.dW1[n * 128 + tid], h);
    h = gelu_f(h);
  }
  float mean = blk_sum<4>(tid < 128 ? h : 0.f, sl + 4) / 128.0f;
  float dv = (tid < 128) ? h - mean : 0.f;
  float var = blk_sum<4>(dv * dv, sl + 8) / 128.0f;
  float feat = (tid < 128) ? dv / sqrtf(var + 1e-5f) * P.dlnw[tid] + P.dlnb[tid]
                           : 0.f;
  float m_c = blk_sum<4>(tid < 128 ? feat * P.mW[tid] : 0.f, sl + 12) + P.mb[0];
  float lv_c = blk_sum<4>(tid < 128 ? feat * P.lvW[tid] : 0.f, sl + 16) + P.lvb[0];
  if (tid == 0) {
    P.out[b * 2 + 0] = m_c;
    P.out[b * 2 + 1] = logf(expf(lv_c) + sumexp);
  }
}

// ---------------- launch-level kernels ----------------

// L0: x partial sums + ds (256 blocks)
__global__ __launch_bounds__(256) void kL0(Params P) {
  int bid = blockIdx.x, tid = threadIdx.x;
  int b = bid >> 4, tc = bid & 15;
  const float* xp = P.x + ((size_t)b * 512 + tc * 32) * 256 + tid;
  float s = 0.f;
  for (int i = 0; i < 32; ++i) s += xp[(size_t)i * 256];
  P.ps[(size_t)bid * 256 + tid] = s;
  if (tc == 0) {
    const float* xb = P.x + (size_t)b * 512 * 256 + tid;
    P.ds[b * 256 + tid] = (xb[(size_t)511 * 256] - xb[0]) / 511.0f;
  }
}

// L1: hidden(0..47) | vcompute(48..79) | ainit rows 0..2047 (80..207)
__global__ __launch_bounds__(256) void kL1(Params P) {
  __shared__ float smem[272];
  int bid = blockIdx.x, tid = threadIdx.x;
  if (bid < 48) phase_hidden(P, smem, bid, tid);
  else if (bid < 80) phase_vcompute(P, bid - 48, tid);
  else phase_ainit(P, smem, (bid - 80) * 16, 16, tid);
}

// L2: gates(0..63) | ainit rows 2048..4095 (64..191)
__global__ __launch_bounds__(256) void kL2(Params P) {
  __shared__ float smem[1440];
  int bid = blockIdx.x, tid = threadIdx.x;
  if (bid < 64) phase_gates(P, smem, bid, tid);
  else phase_ainit(P, smem, 2048 + (bid - 64) * 16, 16, tid);
}

// L3: scan1 (0..255) | ctx (256)
__global__ __launch_bounds__(256) void kL3(Params P) {
  __shared__ float smem[256];
  int bid = blockIdx.x, tid = threadIdx.x;
  if (bid < 256) phase_scan1(P, smem, bid, tid);
  else phase_ctx(P, smem, tid);
}

// L4: mix0 (0..127, 32 rows) | scan2 (128..255)
__global__ __launch_bounds__(256) void kL4(Params P) {
  __shared__ float smem[8];
  int bid = blockIdx.x, tid = threadIdx.x;
  if (bid < 128) phase_mix(P, smem, 0, P.A, P.A2, DK0.a, DK0.b, bid * 32, 32, tid);
  else phase_scan2(P, bid - 128, tid);
}

// L5: mix1 (0..127, 32 rows) | ygemm (128..159)
__global__ __launch_bounds__(256) void kL5(Params P) {
  __shared__ float smem[2120];
  int bid = blockIdx.x, tid = threadIdx.x;
  if (bid < 128) phase_mix(P, smem, 1, P.A2, P.A, DK1.a, DK1.b, bid * 32, 32, tid);
  else phase_ygemm(P, smem, bid - 128, tid);
}

// L6: mix2 (256 blocks, 16 rows)
__global__ __launch_bounds__(256) void kL6(Params P) {
  __shared__ float smem[8];
  int bid = blockIdx.x, tid = threadIdx.x;
  phase_mix(P, smem, 2, P.A, P.A2, DK2.a, DK2.b, bid * 16, 16, tid);
}

// L7/L8/L9: horner hops (128 blocks)
__global__ __launch_bounds__(256) void kL7(Params P) {
  __shared__ float smem[2112];
  phase_horner(P, smem, P.A2, P.YH + 2 * 8192, 0, P.YH + 8192, P.R1,
               blockIdx.x, threadIdx.x);
}
__global__ __launch_bounds__(256) void kL8(Params P) {
  __shared__ float smem[2112];
  phase_horner(P, smem, P.A2, P.R1, 8192, P.YH, P.R2, blockIdx.x, threadIdx.x);
}
__global__ __launch_bounds__(256) void kL9(Params P) {
  __shared__ float smem[2112];
  phase_horner(P, smem, P.A2, P.R2, 8192, nullptr, P.R1, blockIdx.x,
               threadIdx.x);
}

// L10: final + decoder (16 blocks)
__global__ __launch_bounds__(256) void kL10(Params P) {
  __shared__ float smem[276];
  phase_findec(P, smem, blockIdx.x, threadIdx.x);
}

// workspace layout (float offsets)
constexpr size_t O_PS = 0;            // 65536
constexpr size_t O_DS = 65536;        // 4096
constexpr size_t O_HGG = 69632;       // 4096
constexpr size_t O_HGS = 73728;       // 4096
constexpr size_t O_HGA = 77824;       // 4096
constexpr size_t O_FG = 81920;        // 4096
constexpr size_t O_CTX = 86016;       // 320
constexpr size_t O_V = 86336;         // 4096
constexpr size_t O_SV = 90432;        // 64
constexpr size_t O_U = 90496;         // 32768
constexpr size_t O_PF = 123264;       // 524288
constexpr size_t O_QF = 647552;       // 524288
constexpr size_t O_PB = 1171840;      // 524288
constexpr size_t O_QB = 1696128;      // 524288
constexpr size_t O_LF = 2220416;      // 65536
constexpr size_t O_LB = 2285952;      // 65536
constexpr size_t O_YH = 2351488;      // 24576
constexpr size_t O_R1 = 2376064;      // 131072
constexpr size_t O_R2 = 2507136;      // 131072
constexpr size_t O_GM = 2638208;      // 4096
constexpr size_t O_GLV = 2642304;     // 4096
constexpr size_t O_A = 2646400;       // 1048576
constexpr size_t O_A2 = 3694976;      // 1048576
// end = 4743552 floats ~= 19 MB

}  // namespace

extern "C" void kernel_launch(void* const* d_in, const int* in_sizes, int n_in,
                              void* d_out, int out_size, void* d_ws,
                              size_t ws_size, hipStream_t stream) {
  (void)in_sizes; (void)n_in; (void)out_size; (void)ws_size;
  float* w = (float*)d_ws;
  Params prm;
  prm.x = (const float*)d_in[0];
  prm.gW1 = (const float*)d_in[1];
  prm.gb1 = (const float*)d_in[2];
  prm.glnw = (const float*)d_in[3];
  prm.glnb = (const float*)d_in[4];
  prm.gW2 = (const float*)d_in[5];
  prm.gb2 = (const float*)d_in[6];
  prm.sW1 = (const float*)d_in[7];
  prm.sb1 = (const float*)d_in[8];
  prm.sW2 = (const float*)d_in[9];
  prm.sb2 = (const float*)d_in[10];
  prm.aW1 = (const float*)d_in[11];
  prm.ab1 = (const float*)d_in[12];
  prm.aW2 = (const float*)d_in[13];
  prm.ab2 = (const float*)d_in[14];
  prm.g2f = (const float*)d_in[18];
  prm.semb = (const float*)d_in[19];
  prm.aemb = (const float*)d_in[20];
  prm.decay_f = (const float*)d_in[21];
  prm.decay_b = (const float*)d_in[22];
  prm.tW = (const float*)d_in[23];
  prm.tb = (const float*)d_in[24];
  prm.psi = (const float*)d_in[25];
  prm.log_sigma = (const float*)d_in[26];
  prm.step_logits = (const float*)d_in[27];
  prm.noise_scale = (const float*)d_in[28];
  prm.Wk = (const float*)d_in[29];
  prm.mean_w = (const float*)d_in[30];
  prm.mean_b = (const float*)d_in[31];
  prm.lv_w = (const float*)d_in[32];
  prm.lv_b = (const float*)d_in[33];
  prm.dW1 = (const float*)d_in[34];
  prm.db1 = (const float*)d_in[35];
  prm.dlnw = (const float*)d_in[36];
  prm.dlnb = (const float*)d_in[37];
  prm.mW = (const float*)d_in[38];
  prm.mb = (const float*)d_in[39];
  prm.lvW = (const float*)d_in[40];
  prm.lvb = (const float*)d_in[41];
  prm.out = (float*)d_out;
  prm.ps = w + O_PS;
  prm.ds = w + O_DS;
  prm.hgG = w + O_HGG;
  prm.hgS = w + O_HGS;
  prm.hgA = w + O_HGA;
  prm.fg = w + O_FG;
  prm.ctx = w + O_CTX;
  prm.v = w + O_V;
  prm.sv = w + O_SV;
  prm.u = w + O_U;
  prm.Pf = w + O_PF;
  prm.Qf = w + O_QF;
  prm.Pb = w + O_PB;
  prm.Qb = w + O_QB;
  prm.Lf = w + O_LF;
  prm.Lb = w + O_LB;
  prm.YH = w + O_YH;
  prm.R1 = w + O_R1;
  prm.R2 = w + O_R2;
  prm.gm = w + O_GM;
  prm.glv = w + O_GLV;
  prm.A = w + O_A;
  prm.A2 = w + O_A2;

  hipMemsetAsync(w + O_SV, 0, 64 * sizeof(float), stream);
  kL0<<<256, 256, 0, stream>>>(prm);
  kL1<<<208, 256, 0, stream>>>(prm);
  kL2<<<192, 256, 0, stream>>>(prm);
  kL3<<<257, 256, 0, stream>>>(prm);
  kL4<<<256, 256, 0, stream>>>(prm);
  kL5<<<160, 256, 0, stream>>>(prm);
  kL6<<<256, 256, 0, stream>>>(prm);
  kL7<<<128, 256, 0, stream>>>(prm);
  kL8<<<128, 256, 0, stream>>>(prm);
  kL9<<<128, 256, 0, stream>>>(prm);
  kL10<<<16, 256, 0, stream>>>(prm);
}

// Round 6
// 316.743 us; speedup vs baseline: 1.2930x; 1.2930x over previous
//
#include <hip/hip_runtime.h>
#include <stdint.h>

#define PARTITIONABLE 1

namespace {

// ---------------- Threefry-2x32 (constexpr, host+device) ----------------
struct TFPair { uint32_t a, b; };

__host__ __device__ constexpr uint32_t rotl32(uint32_t x, int d) {
  return (x << d) | (x >> (32 - d));
}

__host__ __device__ constexpr TFPair tf2x32(uint32_t k0, uint32_t k1,
                                            uint32_t x0, uint32_t x1) {
  uint32_t k2 = k0 ^ k1 ^ 0x1BD11BDAu;
  x0 += k0; x1 += k1;
  x0 += x1; x1 = rotl32(x1, 13); x1 ^= x0;
  x0 += x1; x1 = rotl32(x1, 15); x1 ^= x0;
  x0 += x1; x1 = rotl32(x1, 26); x1 ^= x0;
  x0 += x1; x1 = rotl32(x1, 6);  x1 ^= x0;
  x0 += k1; x1 += k2 + 1u;
  x0 += x1; x1 = rotl32(x1, 17); x1 ^= x0;
  x0 += x1; x1 = rotl32(x1, 29); x1 ^= x0;
  x0 += x1; x1 = rotl32(x1, 16); x1 ^= x0;
  x0 += x1; x1 = rotl32(x1, 24); x1 ^= x0;
  x0 += k2; x1 += k0 + 2u;
  x0 += x1; x1 = rotl32(x1, 13); x1 ^= x0;
  x0 += x1; x1 = rotl32(x1, 15); x1 ^= x0;
  x0 += x1; x1 = rotl32(x1, 26); x1 ^= x0;
  x0 += x1; x1 = rotl32(x1, 6);  x1 ^= x0;
  x0 += k0; x1 += k1 + 3u;
  x0 += x1; x1 = rotl32(x1, 17); x1 ^= x0;
  x0 += x1; x1 = rotl32(x1, 29); x1 ^= x0;
  x0 += x1; x1 = rotl32(x1, 16); x1 ^= x0;
  x0 += x1; x1 = rotl32(x1, 24); x1 ^= x0;
  x0 += k1; x1 += k2 + 4u;
  x0 += x1; x1 = rotl32(x1, 13); x1 ^= x0;
  x0 += x1; x1 = rotl32(x1, 15); x1 ^= x0;
  x0 += x1; x1 = rotl32(x1, 26); x1 ^= x0;
  x0 += x1; x1 = rotl32(x1, 6);  x1 ^= x0;
  x0 += k2; x1 += k0 + 5u;
  return TFPair{x0, x1};
}

#if PARTITIONABLE
constexpr TFPair KG  = tf2x32(0u, 42u, 0u, 0u);
constexpr TFPair KS  = tf2x32(0u, 42u, 0u, 1u);
constexpr TFPair KA  = tf2x32(0u, 42u, 0u, 2u);
constexpr TFPair KE  = tf2x32(0u, 42u, 0u, 3u);
constexpr TFPair KD  = tf2x32(0u, 42u, 0u, 4u);
constexpr TFPair DK0 = tf2x32(KD.a, KD.b, 0u, 0u);
constexpr TFPair DK1 = tf2x32(KD.a, KD.b, 0u, 1u);
constexpr TFPair DK2 = tf2x32(KD.a, KD.b, 0u, 2u);
#else
constexpr TFPair SP0 = tf2x32(0u, 42u, 0u, 5u);
constexpr TFPair SP1 = tf2x32(0u, 42u, 1u, 6u);
constexpr TFPair SP2 = tf2x32(0u, 42u, 2u, 7u);
constexpr TFPair SP3 = tf2x32(0u, 42u, 3u, 8u);
constexpr TFPair SP4 = tf2x32(0u, 42u, 4u, 9u);
constexpr TFPair KG  = TFPair{SP0.a, SP1.a};
constexpr TFPair KS  = TFPair{SP2.a, SP3.a};
constexpr TFPair KA  = TFPair{SP4.a, SP0.b};
constexpr TFPair KE  = TFPair{SP1.b, SP2.b};
constexpr TFPair KD  = TFPair{SP3.b, SP4.b};
constexpr TFPair DP0 = tf2x32(KD.a, KD.b, 0u, 3u);
constexpr TFPair DP1 = tf2x32(KD.a, KD.b, 1u, 4u);
constexpr TFPair DP2 = tf2x32(KD.a, KD.b, 2u, 5u);
constexpr TFPair DK0 = TFPair{DP0.a, DP1.a};
constexpr TFPair DK1 = TFPair{DP2.a, DP0.b};
constexpr TFPair DK2 = TFPair{DP1.b, DP2.b};
#endif

__device__ __forceinline__ uint32_t rbits(uint32_t k0, uint32_t k1,
                                          uint32_t idx, uint32_t half) {
#if PARTITIONABLE
  TFPair t = tf2x32(k0, k1, 0u, idx);
  return t.a ^ t.b;
#else
  if (idx < half) return tf2x32(k0, k1, idx, idx + half).a;
  return tf2x32(k0, k1, idx - half, idx).b;
#endif
}

__device__ __forceinline__ float bits_to_u01(uint32_t bits) {
  return __uint_as_float((bits >> 9) | 0x3F800000u) - 1.0f;
}

__device__ __forceinline__ float gumbel_u(uint32_t k0, uint32_t k1,
                                          uint32_t idx, uint32_t half) {
  const float mn = 1e-6f;
  const float mx = 1.0f - 1e-6f;
  float f = bits_to_u01(rbits(k0, k1, idx, half));
  return fmaxf(mn, f * (mx - mn) + mn);
}

__device__ __forceinline__ float erfinv_f32(float x) {
  float w = -log1pf(-x * x);
  float p;
  if (w < 5.0f) {
    w -= 2.5f;
    p = 2.81022636e-08f;
    p = fmaf(p, w, 3.43273939e-07f);
    p = fmaf(p, w, -3.5233877e-06f);
    p = fmaf(p, w, -4.39150654e-06f);
    p = fmaf(p, w, 0.00021858087f);
    p = fmaf(p, w, -0.00125372503f);
    p = fmaf(p, w, -0.00417768164f);
    p = fmaf(p, w, 0.246640727f);
    p = fmaf(p, w, 1.50140941f);
  } else {
    w = sqrtf(w) - 3.0f;
    p = -0.000200214257f;
    p = fmaf(p, w, 0.000100950558f);
    p = fmaf(p, w, 0.00134934322f);
    p = fmaf(p, w, -0.00367342844f);
    p = fmaf(p, w, 0.00573950773f);
    p = fmaf(p, w, -0.0076224613f);
    p = fmaf(p, w, 0.00943887047f);
    p = fmaf(p, w, 1.00167406f);
    p = fmaf(p, w, 2.83297682f);
  }
  return p * x;
}

__device__ __forceinline__ float normal_from(uint32_t k0, uint32_t k1,
                                             uint32_t idx, uint32_t half) {
  const float lo = -0x1.fffffep-1f;
  float f = bits_to_u01(rbits(k0, k1, idx, half));
  float u = fmaxf(lo, f * 2.0f + lo);
  return 1.41421356237f * erfinv_f32(u);
}

__device__ __forceinline__ float gelu_f(float x) {
  return 0.5f * x * (1.0f + erff(x / 1.4142135623730951f));
}
__device__ __forceinline__ float sigmoid_f(float x) {
  return 1.0f / (1.0f + expf(-x));
}

__device__ __forceinline__ float wave_sum(float v) {
  #pragma unroll
  for (int m = 32; m > 0; m >>= 1) v += __shfl_xor(v, m);
  return v;
}
__device__ __forceinline__ float wave_max(float v) {
  #pragma unroll
  for (int m = 32; m > 0; m >>= 1) v = fmaxf(v, __shfl_xor(v, m));
  return v;
}
template <int NW>
__device__ __forceinline__ float blk_sum(float v, float* slots) {
  v = wave_sum(v);
  int wid = threadIdx.x >> 6;
  if ((threadIdx.x & 63) == 0) slots[wid] = v;
  __syncthreads();
  float r = slots[0];
  #pragma unroll
  for (int i = 1; i < NW; ++i) r += slots[i];
  return r;
}
template <int NW>
__device__ __forceinline__ float blk_max(float v, float* slots) {
  v = wave_max(v);
  int wid = threadIdx.x >> 6;
  if ((threadIdx.x & 63) == 0) slots[wid] = v;
  __syncthreads();
  float r = slots[0];
  #pragma unroll
  for (int i = 1; i < NW; ++i) r = fmaxf(r, slots[i]);
  return r;
}

// ---------------- params ----------------
struct Params {
  const float *x, *gW1, *gb1, *glnw, *glnb, *gW2, *gb2, *sW1, *sb1, *sW2, *sb2,
      *aW1, *ab1, *aW2, *ab2, *g2f, *semb, *aemb, *decay_f, *decay_b, *tW, *tb,
      *psi, *log_sigma, *step_logits, *noise_scale, *Wk, *mean_w, *mean_b,
      *lv_w, *lv_b, *dW1, *db1, *dlnw, *dlnb, *mW, *mb, *lvW, *lvb;
  float* out;
  float *ps, *ds, *hgG, *hgS, *hgA, *fg, *ctx, *v, *sv, *u, *Pf, *Qf, *Pb, *Qb,
      *Lf, *Lb, *YH, *R1, *R2, *gm, *glv, *A, *A2;
};

// ---------------- device phases ----------------

__device__ __forceinline__ void phase_hidden(const Params& P, float* smem,
                                             int bid, int tid) {
  float* inv = smem;
  float* s1 = smem + 256;
  float* s2 = smem + 260;
  int head = bid >> 4, b = bid & 15;
  float iv;
  if (head < 2) {
    float s = 0.f;
    for (int tc = 0; tc < 16; ++tc) s += P.ps[(size_t)(b * 16 + tc) * 256 + tid];
    iv = s / 512.0f;
  } else {
    iv = P.ds[b * 256 + tid];
  }
  inv[tid] = iv;
  __syncthreads();
  const float* W1 = (head == 0) ? P.gW1 : (head == 1) ? P.sW1 : P.aW1;
  const float* b1 = (head == 0) ? P.gb1 : (head == 1) ? P.sb1 : P.ab1;
  float h = b1[tid];
  for (int d = 0; d < 256; ++d) h = fmaf(inv[d], W1[d * 256 + tid], h);
  if (head == 0) {
    float mean = blk_sum<4>(h, s1) / 256.0f;
    float dv = h - mean;
    float var = blk_sum<4>(dv * dv, s2) / 256.0f;
    h = dv / sqrtf(var + 1e-5f) * P.glnw[tid] + P.glnb[tid];
  }
  float* outp = (head == 0) ? P.hgG : (head == 1) ? P.hgS : P.hgA;
  outp[b * 256 + tid] = gelu_f(h);
}

__device__ __forceinline__ void phase_vcompute(const Params& P, int bid2,
                                               int tid) {
  int j = bid2 >> 2, tg = bid2 & 3;
  const float* wp = (j & 1) ? P.lv_w : P.mean_w;
  const float* Wkk = P.Wk + (size_t)(j >> 1) * 65536;
  int wid = tid >> 6, lane = tid & 63;
  float w0 = wp[lane], w1 = wp[64 + lane];
  float svloc = 0.f;
  for (int i = 0; i < 32; ++i) {
    int t = tg * 128 + wid * 32 + i;
    const float* row = Wkk + (size_t)t * 128;
    float s = row[lane] * w0 + row[64 + lane] * w1;
    s = wave_sum(s);
    if (lane == 0) { P.v[j * 512 + t] = s; svloc += s; }
  }
  if (lane == 0) atomicAdd(&P.sv[j], svloc);
}

// one A0 row per block (full-parallel, r3-proven)
__device__ __forceinline__ void phase_ainit_row(const Params& P, float* smem,
                                                int blk, int tid) {
  float* pn = smem;
  float* s1 = smem + 12;
  float* s2 = smem + 16;
  int mh = blk >> 8, h = mh & 3, n = blk & 255, p = tid;
  if (p < 10) pn[p] = P.psi[(size_t)(h * 256 + n) * 10 + p];
  __syncthreads();
  const float* pp = P.psi + (size_t)(h * 256 + p) * 10;
  float s = 0.f;
  #pragma unroll
  for (int e = 0; e < 10; ++e) s = fmaf(pn[e], pp[e], s);
  float logit = s / sqrtf(10.0f);
  uint32_t idx = (uint32_t)blk * 256u + (uint32_t)p;
  float eps = normal_from(KE.a, KE.b, idx, 524288u);
  float val = logit + expf(P.log_sigma[h]) * eps;
  float mx = blk_max<4>(val, s1);
  float e = expf(val - mx);
  float sum = blk_sum<4>(e, s2);
  P.A[(size_t)blk * 256 + p] = e / sum;
}

__device__ __forceinline__ void phase_gates(const Params& P, float* smem,
                                            int bid, int tid) {
  float* hgGs = smem;
  float* hgSs = smem + 256;
  float* hgAs = smem + 512;
  float* lvS = smem + 768;    // 384
  float* lvA = smem + 1152;   // 256
  float* gsl = smem + 1408;   // 16
  float* gvals = smem + 1424; // 4
  float* gpv = smem + 1428;   // 4
  int b = bid >> 2, f0 = (bid & 3) * 64;
  hgGs[tid] = P.hgG[b * 256 + tid];
  hgSs[tid] = P.hgS[b * 256 + tid];
  hgAs[tid] = P.hgA[b * 256 + tid];
  __syncthreads();
  float lg[4];
  #pragma unroll
  for (int s = 0; s < 4; ++s)
    lg[s] = blk_sum<4>(hgGs[tid] * P.gW2[tid * 4 + s], gsl + 4 * s);
  if (tid < 4) {
    float u = gumbel_u(KG.a, KG.b, (uint32_t)(b * 4 + tid), 32u);
    float g = -logf(-logf(u));
    gvals[tid] = (lg[tid] + P.gb2[tid] + g) / 0.5f;
  }
  __syncthreads();
  if (tid < 4) {
    float mx = fmaxf(fmaxf(gvals[0], gvals[1]), fmaxf(gvals[2], gvals[3]));
    float sum = expf(gvals[0] - mx) + expf(gvals[1] - mx) +
                expf(gvals[2] - mx) + expf(gvals[3] - mx);
    gpv[tid] = expf(gvals[tid] - mx) / sum;
  }
  {
    int o = tid;
    int fl = o / 6, s = o - fl * 6;
    int f = f0 + fl;
    const float* wp = P.sW2 + f * 6 + s;
    float acc = P.sb2[f * 6 + s];
    for (int d = 0; d < 256; ++d) acc = fmaf(hgSs[d], wp[(size_t)d * 1536], acc);
    float u = gumbel_u(KS.a, KS.b, (uint32_t)(b * 256 + f) * 6u + s, 12288u);
    lvS[o] = (acc + (-logf(-logf(u)))) / 0.5f;
  }
  if (tid < 128) {
    int o = tid + 256;
    int fl = o / 6, s = o - fl * 6;
    int f = f0 + fl;
    const float* wp = P.sW2 + f * 6 + s;
    float acc = P.sb2[f * 6 + s];
    for (int d = 0; d < 256; ++d) acc = fmaf(hgSs[d], wp[(size_t)d * 1536], acc);
    float u = gumbel_u(KS.a, KS.b, (uint32_t)(b * 256 + f) * 6u + s, 12288u);
    lvS[o] = (acc + (-logf(-logf(u)))) / 0.5f;
  }
  {
    int fl = tid >> 2, s = tid & 3;
    int f = f0 + fl;
    const float* wp = P.aW2 + f * 4 + s;
    float acc = P.ab2[f * 4 + s];
    for (int d = 0; d < 256; ++d) acc = fmaf(hgAs[d], wp[(size_t)d * 1024], acc);
    float u = gumbel_u(KA.a, KA.b, (uint32_t)(b * 256 + f) * 4u + s, 8192u);
    lvA[tid] = (acc + (-logf(-logf(u)))) / 0.5f;
  }
  __syncthreads();
  if (tid < 64) {
    int f = f0 + tid;
    float v0 = lvS[tid * 6 + 0], v1 = lvS[tid * 6 + 1], v2 = lvS[tid * 6 + 2];
    float v3 = lvS[tid * 6 + 3], v4 = lvS[tid * 6 + 4], v5 = lvS[tid * 6 + 5];
    float mx = fmaxf(fmaxf(fmaxf(v0, v1), fmaxf(v2, v3)), fmaxf(v4, v5));
    float e0 = expf(v0 - mx), e1 = expf(v1 - mx), e2 = expf(v2 - mx);
    float e3 = expf(v3 - mx), e4 = expf(v4 - mx), e5 = expf(v5 - mx);
    float ssum = e0 + e1 + e2 + e3 + e4 + e5;
    float sg = (e0 / ssum) * P.semb[0 * 256 + f] + (e1 / ssum) * P.semb[1 * 256 + f] +
               (e2 / ssum) * P.semb[2 * 256 + f] + (e3 / ssum) * P.semb[3 * 256 + f] +
               (e4 / ssum) * P.semb[4 * 256 + f] + (e5 / ssum) * P.semb[5 * 256 + f];
    float a0 = lvA[tid * 4 + 0], a1 = lvA[tid * 4 + 1];
    float a2 = lvA[tid * 4 + 2], a3 = lvA[tid * 4 + 3];
    float amx = fmaxf(fmaxf(a0, a1), fmaxf(a2, a3));
    float x0 = expf(a0 - amx), x1 = expf(a1 - amx);
    float x2 = expf(a2 - amx), x3 = expf(a3 - amx);
    float asum = x0 + x1 + x2 + x3;
    float ag = (x0 / asum) * P.aemb[0 * 256 + f] + (x1 / asum) * P.aemb[1 * 256 + f] +
               (x2 / asum) * P.aemb[2 * 256 + f] + (x3 / asum) * P.aemb[3 * 256 + f];
    float gg = 0.f;
    #pragma unroll
    for (int s = 0; s < 4; ++s) gg = fmaf(gpv[s], P.g2f[s * 256 + f], gg);
    P.fg[b * 256 + f] = sigmoid_f(gg + sg + ag);
  }
}

__device__ __forceinline__ void phase_ctx(const Params& P, float* smem,
                                          int tid) {
  float* s1 = smem;
  float* s2 = smem + 4;
  float c = 0.f;
  for (int b = 0; b < 16; ++b) c += P.fg[b * 256 + tid];
  c /= 16.0f;
  float ss = blk_sum<4>(c * c, s1);
  float cv = c / (sqrtf(ss) + 1e-6f);
  P.ctx[tid] = cv;
  float S = blk_sum<4>(cv, s2);
  if (tid == 0) P.ctx[256] = S;
}

__device__ __forceinline__ void phase_scan1(const Params& P, float* smem,
                                            int ch, int tid) {
  float* vv = smem;  // [8][32]
  int b = ch >> 4, c = ch & 15;
  int d = tid;
  vv[(d >> 5) * 32 + (d & 31)] = P.v[(d >> 5) * 512 + c * 32 + (d & 31)];
  __syncthreads();
  float g = P.fg[b * 256 + d];
  float af = sigmoid_f(P.decay_f[d]);
  float ab = sigmoid_f(P.decay_b[d]);
  float r_gx[32];
  const float* xp = P.x + ((size_t)b * 512 + c * 32) * 256 + d;
  #pragma unroll
  for (int i = 0; i < 32; ++i) r_gx[i] = xp[(size_t)i * 256] * g;
  float h = 0.f, pw = 1.f;
  float Pr[8], Q[8];
  #pragma unroll
  for (int j = 0; j < 8; ++j) { Pr[j] = 0.f; Q[j] = 0.f; }
  #pragma unroll
  for (int i = 0; i < 32; ++i) {
    h = fmaf(af, h, (1.0f - af) * r_gx[i]);
    pw *= af;
    #pragma unroll
    for (int j = 0; j < 8; ++j) {
      float vj = vv[j * 32 + i];
      Pr[j] = fmaf(h, vj, Pr[j]);
      Q[j] = fmaf(pw, vj, Q[j]);
    }
  }
  size_t base = ((size_t)(b * 16 + c) * 8) * 256 + d;
  #pragma unroll
  for (int j = 0; j < 8; ++j) {
    P.Pf[base + j * 256] = Pr[j];
    P.Qf[base + j * 256] = Q[j];
  }
  P.Lf[(b * 16 + c) * 256 + d] = h;
  h = 0.f; pw = 1.f;
  #pragma unroll
  for (int j = 0; j < 8; ++j) { Pr[j] = 0.f; Q[j] = 0.f; }
  #pragma unroll
  for (int i = 31; i >= 0; --i) {
    h = fmaf(ab, h, (1.0f - ab) * r_gx[i]);
    pw *= ab;
    #pragma unroll
    for (int j = 0; j < 8; ++j) {
      float vj = vv[j * 32 + i];
      Pr[j] = fmaf(h, vj, Pr[j]);
      Q[j] = fmaf(pw, vj, Q[j]);
    }
  }
  #pragma unroll
  for (int j = 0; j < 8; ++j) {
    P.Pb[base + j * 256] = Pr[j];
    P.Qb[base + j * 256] = Q[j];
  }
  P.Lb[(b * 16 + c) * 256 + d] = h;
}

__device__ __forceinline__ void phase_scan2(const Params& P, int blk, int tid) {
  int b = blk >> 3, j = blk & 7;
  int d = tid;
  float af = sigmoid_f(P.decay_f[d]);
  float ab = sigmoid_f(P.decay_b[d]);
  float af32 = af, ab32 = ab;
  #pragma unroll
  for (int q = 0; q < 5; ++q) { af32 *= af32; ab32 *= ab32; }
  float acc = 0.f, H = 0.f;
  for (int c = 0; c < 16; ++c) {
    size_t base = ((size_t)(b * 16 + c) * 8 + j) * 256 + d;
    acc += P.Pf[base] + H * P.Qf[base];
    H = P.Lf[(b * 16 + c) * 256 + d] + af32 * H;
  }
  H = 0.f;
  for (int c = 15; c >= 0; --c) {
    size_t base = ((size_t)(b * 16 + c) * 8 + j) * 256 + d;
    acc += P.Pb[base] + H * P.Qb[base];
    H = P.Lb[(b * 16 + c) * 256 + d] + ab32 * H;
  }
  P.u[(b * 8 + j) * 256 + d] = acc;
}

__device__ __forceinline__ void phase_ygemm(const Params& P, float* smem,
                                            int blk32, int tid) {
  float* As = smem;            // 32*33
  float* Bs = smem + 1056;     // 32*33
  float* svs = smem + 2112;    // 8
  int n0 = (blk32 & 7) * 32, m0 = (blk32 >> 3) * 32;
  int tx = tid & 31, ty = tid >> 5;
  if (tid < 8) svs[tid] = P.sv[tid];
  float acc[4] = {0.f, 0.f, 0.f, 0.f};
  for (int k0 = 0; k0 < 256; k0 += 32) {
    #pragma unroll
    for (int l = 0; l < 4; ++l) {
      int e = tid + l * 256, r = e >> 5, cc = e & 31;
      As[r * 33 + cc] = P.u[(size_t)(m0 + r) * 256 + k0 + cc];
      Bs[r * 33 + cc] = P.tW[(size_t)(k0 + r) * 256 + n0 + cc];
    }
    __syncthreads();
    #pragma unroll
    for (int kk = 0; kk < 32; ++kk) {
      float bv = Bs[kk * 33 + tx];
      #pragma unroll
      for (int i = 0; i < 4; ++i)
        acc[i] = fmaf(As[(ty + 8 * i) * 33 + kk], bv, acc[i]);
    }
    __syncthreads();
  }
  int n = n0 + tx;
  float tbn = P.tb[n];
  float mb0 = P.mean_b[0], lb0 = P.lv_b[0];
  #pragma unroll
  for (int i = 0; i < 4; ++i) {
    int row = m0 + ty + 8 * i;
    int b = row >> 3, j = row & 7;
    float val = acc[i] + tbn * svs[j];
    if (j == 0) P.gm[b * 256 + n] = val + mb0;
    else if (j == 1) P.glv[b * 256 + n] = val + lb0;
    else {
      int k = (j >> 1) - 1, proj = j & 1;
      P.YH[k * 8192 + n * 32 + b * 2 + proj] = val;
    }
  }
}

// one diffusion-mix row per block (full-parallel, r3-proven)
__device__ __forceinline__ void phase_mix_row(const Params& P, float* smem,
                                              int sidx, const float* Ain,
                                              float* Aout, uint32_t dk0,
                                              uint32_t dk1, int blk, int tid) {
  float* s1 = smem;
  float* s2 = smem + 4;
  float alpha = sigmoid_f(P.step_logits[sidx]);
  float ns = P.noise_scale[sidx];
  float S = P.ctx[256];
  float cp = P.ctx[tid];
  int mh = blk >> 8, n = blk & 255, p = tid;
  float cn = P.ctx[n];
  float o_np = (cn * cp) / fmaxf(cn * S, 1e-6f);
  float o_pn = (cp * cn) / fmaxf(cp * S, 1e-6f);
  uint32_t i_np = (uint32_t)blk * 256u + (uint32_t)p;
  uint32_t i_pn = (uint32_t)mh * 65536u + (uint32_t)p * 256u + (uint32_t)n;
  float a_np = Ain[(size_t)mh * 65536 + n * 256 + p];
  float a_pn = Ain[(size_t)mh * 65536 + p * 256 + n];
  float m_np = alpha * a_np + (1.0f - alpha) * o_np +
               ns * normal_from(dk0, dk1, i_np, 524288u);
  float m_pn = alpha * a_pn + (1.0f - alpha) * o_pn +
               ns * normal_from(dk0, dk1, i_pn, 524288u);
  float val = 0.5f * (m_np + m_pn);
  float mx = blk_max<4>(val, s1);
  float e = expf(val - mx);
  float sum = blk_sum<4>(e, s2);
  Aout[(size_t)blk * 256 + p] = e / sum;
}

__device__ __forceinline__ void phase_horner(const Params& P, float* smem,
                                             const float* A, const float* Rin,
                                             int sRin, const float* Yadd,
                                             float* Rout, int bid, int tid) {
  float* As = smem;
  float* Bs = smem + 1056;
  int nt = bid & 7, mh = bid >> 3;
  int n0 = nt * 32;
  int tx = tid & 31, ty = tid >> 5;
  float acc[4] = {0.f, 0.f, 0.f, 0.f};
  const float* Ab = A + (size_t)mh * 65536;
  const float* Rb = Rin + (size_t)mh * sRin;
  for (int k0 = 0; k0 < 256; k0 += 32) {
    #pragma unroll
    for (int l = 0; l < 4; ++l) {
      int e = tid + l * 256, r = e >> 5, cc = e & 31;
      As[r * 33 + cc] = Ab[(size_t)(n0 + r) * 256 + k0 + cc];
      Bs[r * 33 + cc] = Rb[(size_t)(k0 + r) * 32 + cc];
    }
    __syncthreads();
    #pragma unroll
    for (int kk = 0; kk < 32; ++kk) {
      float bv = Bs[kk * 33 + tx];
      #pragma unroll
      for (int i = 0; i < 4; ++i)
        acc[i] = fmaf(As[(ty + 8 * i) * 33 + kk], bv, acc[i]);
    }
    __syncthreads();
  }
  #pragma unroll
  for (int i = 0; i < 4; ++i) {
    int n = n0 + ty + 8 * i;
    float vv = acc[i];
    if (Yadd) vv += Yadd[n * 32 + tx];
    Rout[(size_t)mh * 8192 + (size_t)n * 32 + tx] = vv;
  }
}

__device__ __forceinline__ void phase_findec(const Params& P, float* smem,
                                             int bid, int tid) {
  float* gmv = smem;       // 256
  float* sl = smem + 256;  // 20
  int b = bid;
  float sm_ = 0.f, sl_ = 0.f;
  for (int mh = 0; mh < 16; ++mh) {
    sm_ += P.R1[(size_t)mh * 8192 + tid * 32 + b * 2];
    sl_ += P.R1[(size_t)mh * 8192 + tid * 32 + b * 2 + 1];
  }
  float gmn = P.gm[b * 256 + tid] + sm_ * (1.0f / 16.0f);
  float gln = P.glv[b * 256 + tid] + sl_ * (1.0f / 16.0f);
  gmv[tid] = gmn;
  float se = expf(gln);
  __syncthreads();
  float sumexp = blk_sum<4>(se, sl);
  float h = 0.f;
  if (tid < 128) {
    h = P.db1[tid];
    for (int n = 0; n < 256; ++n) h = fmaf(gmv[n], P.dW1[n * 128 + tid], h);
    h = gelu_f(h);
  }
  float mean = blk_sum<4>(tid < 128 ? h : 0.f, sl + 4) / 128.0f;
  float dv = (tid < 128) ? h - mean : 0.f;
  float var = blk_sum<4>(dv * dv, sl + 8) / 128.0f;
  float feat = (tid < 128) ? dv / sqrtf(var + 1e-5f) * P.dlnw[tid] + P.dlnb[tid]
                           : 0.f;
  float m_c = blk_sum<4>(tid < 128 ? feat * P.mW[tid] : 0.f, sl + 12) + P.mb[0];
  float lv_c = blk_sum<4>(tid < 128 ? feat * P.lvW[tid] : 0.f, sl + 16) + P.lvb[0];
  if (tid == 0) {
    P.out[b * 2 + 0] = m_c;
    P.out[b * 2 + 1] = logf(expf(lv_c) + sumexp);
  }
}

// ---------------- launch-level kernels ----------------

// L0: x partial sums + ds + sv zero (256 blocks)
__global__ __launch_bounds__(256) void kL0(Params P) {
  int bid = blockIdx.x, tid = threadIdx.x;
  int b = bid >> 4, tc = bid & 15;
  const float* xp = P.x + ((size_t)b * 512 + tc * 32) * 256 + tid;
  float s = 0.f;
  for (int i = 0; i < 32; ++i) s += xp[(size_t)i * 256];
  P.ps[(size_t)bid * 256 + tid] = s;
  if (tc == 0) {
    const float* xb = P.x + (size_t)b * 512 * 256 + tid;
    P.ds[b * 256 + tid] = (xb[(size_t)511 * 256] - xb[0]) / 511.0f;
  }
  if (bid == 0 && tid < 8) P.sv[tid] = 0.f;
}

// LA: ainit (4096 blocks, one row each)
__global__ __launch_bounds__(256) void kLA(Params P) {
  __shared__ float smem[20];
  phase_ainit_row(P, smem, blockIdx.x, threadIdx.x);
}

// LB: hidden(0..47) | vcompute(48..79)
__global__ __launch_bounds__(256) void kLB(Params P) {
  __shared__ float smem[272];
  int bid = blockIdx.x, tid = threadIdx.x;
  if (bid < 48) phase_hidden(P, smem, bid, tid);
  else phase_vcompute(P, bid - 48, tid);
}

// LC: gates (64)
__global__ __launch_bounds__(256) void kLC(Params P) {
  __shared__ float smem[1440];
  phase_gates(P, smem, blockIdx.x, threadIdx.x);
}

// LD: scan1 (0..255) | ctx (256)
__global__ __launch_bounds__(256) void kLD(Params P) {
  __shared__ float smem[256];
  int bid = blockIdx.x, tid = threadIdx.x;
  if (bid < 256) phase_scan1(P, smem, bid, tid);
  else phase_ctx(P, smem, tid);
}

// M0: mix0 rows (0..4095) | scan2 (4096..4223)
__global__ __launch_bounds__(256) void kM0(Params P) {
  __shared__ float smem[8];
  int bid = blockIdx.x, tid = threadIdx.x;
  if (bid < 4096) phase_mix_row(P, smem, 0, P.A, P.A2, DK0.a, DK0.b, bid, tid);
  else phase_scan2(P, bid - 4096, tid);
}

// M1: mix1 rows (0..4095) | ygemm (4096..4127)
__global__ __launch_bounds__(256) void kM1(Params P) {
  __shared__ float smem[2120];
  int bid = blockIdx.x, tid = threadIdx.x;
  if (bid < 4096) phase_mix_row(P, smem, 1, P.A2, P.A, DK1.a, DK1.b, bid, tid);
  else phase_ygemm(P, smem, bid - 4096, tid);
}

// M2: mix2 rows (4096)
__global__ __launch_bounds__(256) void kM2(Params P) {
  __shared__ float smem[8];
  phase_mix_row(P, smem, 2, P.A, P.A2, DK2.a, DK2.b, blockIdx.x, threadIdx.x);
}

// H1/H2/H3: horner hops (128 blocks)
__global__ __launch_bounds__(256) void kH1(Params P) {
  __shared__ float smem[2112];
  phase_horner(P, smem, P.A2, P.YH + 2 * 8192, 0, P.YH + 8192, P.R1,
               blockIdx.x, threadIdx.x);
}
__global__ __launch_bounds__(256) void kH2(Params P) {
  __shared__ float smem[2112];
  phase_horner(P, smem, P.A2, P.R1, 8192, P.YH, P.R2, blockIdx.x, threadIdx.x);
}
__global__ __launch_bounds__(256) void kH3(Params P) {
  __shared__ float smem[2112];
  phase_horner(P, smem, P.A2, P.R2, 8192, nullptr, P.R1, blockIdx.x,
               threadIdx.x);
}

// Fin: final + decoder (16 blocks)
__global__ __launch_bounds__(256) void kFin(Params P) {
  __shared__ float smem[276];
  phase_findec(P, smem, blockIdx.x, threadIdx.x);
}

// workspace layout (float offsets)
constexpr size_t O_PS = 0;            // 65536
constexpr size_t O_DS = 65536;        // 4096
constexpr size_t O_HGG = 69632;       // 4096
constexpr size_t O_HGS = 73728;       // 4096
constexpr size_t O_HGA = 77824;       // 4096
constexpr size_t O_FG = 81920;        // 4096
constexpr size_t O_CTX = 86016;       // 320
constexpr size_t O_V = 86336;         // 4096
constexpr size_t O_SV = 90432;        // 64
constexpr size_t O_U = 90496;         // 32768
constexpr size_t O_PF = 123264;       // 524288
constexpr size_t O_QF = 647552;       // 524288
constexpr size_t O_PB = 1171840;      // 524288
constexpr size_t O_QB = 1696128;      // 524288
constexpr size_t O_LF = 2220416;      // 65536
constexpr size_t O_LB = 2285952;      // 65536
constexpr size_t O_YH = 2351488;      // 24576
constexpr size_t O_R1 = 2376064;      // 131072
constexpr size_t O_R2 = 2507136;      // 131072
constexpr size_t O_GM = 2638208;      // 4096
constexpr size_t O_GLV = 2642304;     // 4096
constexpr size_t O_A = 2646400;       // 1048576
constexpr size_t O_A2 = 3694976;      // 1048576
// end = 4743552 floats ~= 19 MB

}  // namespace

extern "C" void kernel_launch(void* const* d_in, const int* in_sizes, int n_in,
                              void* d_out, int out_size, void* d_ws,
                              size_t ws_size, hipStream_t stream) {
  (void)in_sizes; (void)n_in; (void)out_size; (void)ws_size;
  float* w = (float*)d_ws;
  Params prm;
  prm.x = (const float*)d_in[0];
  prm.gW1 = (const float*)d_in[1];
  prm.gb1 = (const float*)d_in[2];
  prm.glnw = (const float*)d_in[3];
  prm.glnb = (const float*)d_in[4];
  prm.gW2 = (const float*)d_in[5];
  prm.gb2 = (const float*)d_in[6];
  prm.sW1 = (const float*)d_in[7];
  prm.sb1 = (const float*)d_in[8];
  prm.sW2 = (const float*)d_in[9];
  prm.sb2 = (const float*)d_in[10];
  prm.aW1 = (const float*)d_in[11];
  prm.ab1 = (const float*)d_in[12];
  prm.aW2 = (const float*)d_in[13];
  prm.ab2 = (const float*)d_in[14];
  prm.g2f = (const float*)d_in[18];
  prm.semb = (const float*)d_in[19];
  prm.aemb = (const float*)d_in[20];
  prm.decay_f = (const float*)d_in[21];
  prm.decay_b = (const float*)d_in[22];
  prm.tW = (const float*)d_in[23];
  prm.tb = (const float*)d_in[24];
  prm.psi = (const float*)d_in[25];
  prm.log_sigma = (const float*)d_in[26];
  prm.step_logits = (const float*)d_in[27];
  prm.noise_scale = (const float*)d_in[28];
  prm.Wk = (const float*)d_in[29];
  prm.mean_w = (const float*)d_in[30];
  prm.mean_b = (const float*)d_in[31];
  prm.lv_w = (const float*)d_in[32];
  prm.lv_b = (const float*)d_in[33];
  prm.dW1 = (const float*)d_in[34];
  prm.db1 = (const float*)d_in[35];
  prm.dlnw = (const float*)d_in[36];
  prm.dlnb = (const float*)d_in[37];
  prm.mW = (const float*)d_in[38];
  prm.mb = (const float*)d_in[39];
  prm.lvW = (const float*)d_in[40];
  prm.lvb = (const float*)d_in[41];
  prm.out = (float*)d_out;
  prm.ps = w + O_PS;
  prm.ds = w + O_DS;
  prm.hgG = w + O_HGG;
  prm.hgS = w + O_HGS;
  prm.hgA = w + O_HGA;
  prm.fg = w + O_FG;
  prm.ctx = w + O_CTX;
  prm.v = w + O_V;
  prm.sv = w + O_SV;
  prm.u = w + O_U;
  prm.Pf = w + O_PF;
  prm.Qf = w + O_QF;
  prm.Pb = w + O_PB;
  prm.Qb = w + O_QB;
  prm.Lf = w + O_LF;
  prm.Lb = w + O_LB;
  prm.YH = w + O_YH;
  prm.R1 = w + O_R1;
  prm.R2 = w + O_R2;
  prm.gm = w + O_GM;
  prm.glv = w + O_GLV;
  prm.A = w + O_A;
  prm.A2 = w + O_A2;

  kL0<<<256, 256, 0, stream>>>(prm);
  kLA<<<4096, 256, 0, stream>>>(prm);
  kLB<<<80, 256, 0, stream>>>(prm);
  kLC<<<64, 256, 0, stream>>>(prm);
  kLD<<<257, 256, 0, stream>>>(prm);
  kM0<<<4224, 256, 0, stream>>>(prm);
  kM1<<<4128, 256, 0, stream>>>(prm);
  kM2<<<4096, 256, 0, stream>>>(prm);
  kH1<<<128, 256, 0, stream>>>(prm);
  kH2<<<128, 256, 0, stream>>>(prm);
  kH3<<<128, 256, 0, stream>>>(prm);
  kFin<<<16, 256, 0, stream>>>(prm);
}